// Round 1
// baseline (3686.578 us; speedup 1.0000x reference)
//
#include <hip/hip_runtime.h>
#include <math.h>

// Problem constants (match reference)
#define NB 512
#define NS 17
#define NL 81
#define NV 13030
#define NENC 240
#define NOE 80
#define NPE 60
#define NH 200
#define NIN 380   // ENC+OE+PE
#define NG 800    // 4*H

// ---------------- threefry2x32 (bit-exact vs JAX) ----------------
__device__ __forceinline__ unsigned rotl32(unsigned x, int d) {
  return (x << d) | (x >> (32 - d));
}

__device__ __forceinline__ void threefry2x32(unsigned k0, unsigned k1,
                                             unsigned x0, unsigned x1,
                                             unsigned& y0, unsigned& y1) {
  unsigned ks2 = k0 ^ k1 ^ 0x1BD11BDAu;
  x0 += k0; x1 += k1;
#define TFR(r) { x0 += x1; x1 = rotl32(x1, r); x1 ^= x0; }
  TFR(13) TFR(15) TFR(26) TFR(6)
  x0 += k1;  x1 += ks2 + 1u;
  TFR(17) TFR(29) TFR(16) TFR(24)
  x0 += ks2; x1 += k0 + 2u;
  TFR(13) TFR(15) TFR(26) TFR(6)
  x0 += k0;  x1 += k1 + 3u;
  TFR(17) TFR(29) TFR(16) TFR(24)
  x0 += k1;  x1 += ks2 + 4u;
  TFR(13) TFR(15) TFR(26) TFR(6)
  x0 += ks2; x1 += k0 + 5u;
#undef TFR
  y0 = x0; y1 = x1;
}

// keys = reshape(threefry2x32(key(42), iota(2*NS)), (NS,2)); element i of the
// flat output: i<NS -> lane0 of block (i, i+NS); else lane1 of block (i-NS, i).
__device__ __forceinline__ unsigned split_key_elem(unsigned i) {
  unsigned y0, y1;
  if (i < (unsigned)NS) { threefry2x32(0u, 42u, i, i + (unsigned)NS, y0, y1); return y0; }
  threefry2x32(0u, 42u, i - (unsigned)NS, i, y0, y1);
  return y1;
}

// uniform(minval=tiny): u=((bits>>9)|0x3f800000)-1; *(1-tiny)==*1; +tiny only
// matters at u==0; then gumbel = -log(-log(u)).
__device__ __forceinline__ float gumbel_from_bits(unsigned bits) {
  float u = __uint_as_float((bits >> 9) | 0x3f800000u) - 1.0f;
  if (u == 0.0f) u = 1.17549435e-38f;
  return -logf(-logf(u));
}

// ---------------- tiled fp32 NT GEMM helper: C[m,n] += A[m,:K]·Bw[n,:K] ------
#define BM 64
#define BN 64
#define BKC 8
#define LDT 68  // LDS row stride (pad: 64+4)

__device__ __forceinline__ void gemm_nt_accum(
    const float* __restrict__ A, const float* __restrict__ Bw,
    int M, int N, int K, int m0, int n0,
    float acc[4][4], float* As, float* Bs) {
  const int tid  = threadIdx.x;
  const int ty   = tid >> 4;        // 0..15
  const int tx   = tid & 15;        // 0..15
  const int lrow = tid >> 2;        // 0..63
  const int lk   = (tid & 3) * 2;   // 0,2,4,6
  const int nk = (K + BKC - 1) / BKC;
  for (int kc = 0; kc < nk; ++kc) {
    const int k0 = kc * BKC;
    {
      int gm = m0 + lrow;
      float a0 = 0.f, a1 = 0.f;
      if (gm < M) {
        if (k0 + lk < K)     a0 = A[(size_t)gm * K + k0 + lk];
        if (k0 + lk + 1 < K) a1 = A[(size_t)gm * K + k0 + lk + 1];
      }
      As[lk * LDT + lrow]       = a0;
      As[(lk + 1) * LDT + lrow] = a1;
      int gn = n0 + lrow;
      float b0 = 0.f, b1 = 0.f;
      if (gn < N) {
        if (k0 + lk < K)     b0 = Bw[(size_t)gn * K + k0 + lk];
        if (k0 + lk + 1 < K) b1 = Bw[(size_t)gn * K + k0 + lk + 1];
      }
      Bs[lk * LDT + lrow]       = b0;
      Bs[(lk + 1) * LDT + lrow] = b1;
    }
    __syncthreads();
#pragma unroll
    for (int kk = 0; kk < BKC; ++kk) {
      float av[4], bv[4];
#pragma unroll
      for (int i = 0; i < 4; ++i) av[i] = As[kk * LDT + ty * 4 + i];
#pragma unroll
      for (int j = 0; j < 4; ++j) bv[j] = Bs[kk * LDT + tx * 4 + j];
#pragma unroll
      for (int i = 0; i < 4; ++i)
#pragma unroll
        for (int j = 0; j < 4; ++j)
          acc[i][j] = fmaf(av[i], bv[j], acc[i][j]);
    }
    __syncthreads();
  }
}

// ---------------- one-time prep: power_emb + invalid ----------------
__global__ void __launch_bounds__(256) init_kernel(
    const float* __restrict__ power_1h, const float* __restrict__ power_W,
    const float* __restrict__ power_b, const int* __restrict__ loc_idxs,
    float* __restrict__ power_emb, int* __restrict__ invalid) {
  int t = blockIdx.x * 256 + threadIdx.x;
  if (t < NB * NPE) {
    int b = t / NPE, p = t % NPE;
    float a = power_b[p];
#pragma unroll
    for (int k = 0; k < 7; ++k) a = fmaf(power_1h[b * 7 + k], power_W[p * 7 + k], a);
    power_emb[t] = a;
  }
  if (t < NB) {
    bool any = false;
    for (int l = 0; l < NL; ++l) any = any || (loc_idxs[t * NL + l] != -1);
    invalid[t] = any ? 0 : 1;
  }
}

// ---------------- per-step: alignment + loc_enc + concat into x -------------
__global__ void __launch_bounds__(256) build_x_kernel(
    const int* __restrict__ loc_idxs, const float* __restrict__ MA,
    const float* __restrict__ enc, const float* __restrict__ order_emb,
    const float* __restrict__ power_emb, float* __restrict__ x, int step) {
  __shared__ float sel[NL];
  __shared__ float aln[NL];
  __shared__ float denom;
  const int b = blockIdx.x, tid = threadIdx.x;
  if (tid < NL) {
    int li = loc_idxs[b * NL + tid];
    sel[tid] = (li == step || li == -2) ? 1.0f : 0.0f;
  }
  __syncthreads();
  if (tid < NL) {
    float a = 0.f;
    for (int l = 0; l < NL; ++l) a = fmaf(sel[l], MA[l * NL + tid], a);
    aln[tid] = a;
  }
  __syncthreads();
  if (tid == 0) {
    float d = 0.f;
    for (int l = 0; l < NL; ++l) d += aln[l];
    denom = d;
  }
  __syncthreads();
  if (tid < NL) aln[tid] = (denom != 0.f) ? aln[tid] / denom : 0.0f;
  __syncthreads();
  float* xb = x + (size_t)b * NIN;
  for (int d = tid; d < NENC; d += 256) {
    const float* eb = enc + (size_t)b * NL * NENC + d;
    float a = 0.f;
    for (int l = 0; l < NL; ++l) a = fmaf(aln[l], eb[(size_t)l * NENC], a);
    xb[d] = a;
  }
  if (tid < NOE) xb[NENC + tid] = order_emb[b * NOE + tid];
  if (tid < NPE) xb[NENC + NOE + tid] = power_emb[b * NPE + tid];
}

// ---------------- per-step: gates = x@W_ih^T + h@W_hh^T + b_ih + b_hh -------
__global__ void __launch_bounds__(256) gates_kernel(
    const float* __restrict__ x, const float* __restrict__ h,
    const float* __restrict__ W_ih, const float* __restrict__ W_hh,
    const float* __restrict__ b_ih, const float* __restrict__ b_hh,
    float* __restrict__ gates) {
  __shared__ float As[BKC * LDT];
  __shared__ float Bs[BKC * LDT];
  const int m0 = blockIdx.y * BM;
  const int n0 = blockIdx.x * BN;
  float acc[4][4] = {{0.f}};
  gemm_nt_accum(x, W_ih, NB, NG, NIN, m0, n0, acc, As, Bs);
  gemm_nt_accum(h, W_hh, NB, NG, NH, m0, n0, acc, As, Bs);
  const int ty = threadIdx.x >> 4, tx = threadIdx.x & 15;
#pragma unroll
  for (int i = 0; i < 4; ++i) {
    int m = m0 + ty * 4 + i;
#pragma unroll
    for (int j = 0; j < 4; ++j) {
      int n = n0 + tx * 4 + j;
      if (n < NG) gates[(size_t)m * NG + n] = acc[i][j] + b_ih[n] + b_hh[n];
    }
  }
}

// ---------------- per-step: LSTM cell elementwise ----------------
__global__ void __launch_bounds__(256) lstm_cell_kernel(
    const float* __restrict__ gates, float* __restrict__ h, float* __restrict__ c) {
  int t = blockIdx.x * 256 + threadIdx.x;
  if (t >= NB * NH) return;
  int b = t / NH, j = t % NH;
  const float* g = gates + (size_t)b * NG;
  float gi = g[j], gf = g[NH + j], gg = g[2 * NH + j], go = g[3 * NH + j];
  float si = 1.f / (1.f + expf(-gi));
  float sf = 1.f / (1.f + expf(-gf));
  float so = 1.f / (1.f + expf(-go));
  float cn = sf * c[t] + si * tanhf(gg);
  float hn = so * tanhf(cn);
  c[t] = cn;
  h[t] = hn;
}

// ---------------- per-step: scores = h@out_W^T + out_b, masked, -> d_out ----
__global__ void __launch_bounds__(256) scores_kernel(
    const float* __restrict__ h, const float* __restrict__ out_W,
    const float* __restrict__ out_b, const int* __restrict__ order_masks,
    const int* __restrict__ invalid, float* __restrict__ out, int step) {
  __shared__ float As[BKC * LDT];
  __shared__ float Bs[BKC * LDT];
  const int m0 = blockIdx.y * BM;
  const int n0 = blockIdx.x * BN;
  float acc[4][4] = {{0.f}};
  gemm_nt_accum(h, out_W, NB, NV, NH, m0, n0, acc, As, Bs);
  const int ty = threadIdx.x >> 4, tx = threadIdx.x & 15;
#pragma unroll
  for (int i = 0; i < 4; ++i) {
    int m = m0 + ty * 4 + i;
    int inv = invalid[m];
#pragma unroll
    for (int j = 0; j < 4; ++j) {
      int n = n0 + tx * 4 + j;
      if (n < NV) {
        float val = acc[i][j] + out_b[n];
        int msk = inv ? 1 : order_masks[(size_t)m * NS * NV + (size_t)step * NV + n];
        float cap = msk ? 9.0e8f : -1.0e8f;  // m*1e9 - 1e8, exact in fp32
        val = fminf(val, cap);
        out[(size_t)NB * NS + (size_t)m * NS * NV + (size_t)step * NV + n] = val;
      }
    }
  }
}

// ---------------- per-step: gumbel-argmax sample + order_emb gather ---------
// Block bl handles batch rows bl and bl+256; positions j=bl*NV+v and j+n/2
// share one threefry block (lane0 -> row bl, lane1 -> row bl+256).
__global__ void __launch_bounds__(256) sample_kernel(
    float* __restrict__ out, const float* __restrict__ order_embedding,
    float* __restrict__ order_emb, int step) {
  const int bl = blockIdx.x;        // 0..255
  const int bh = bl + 256;
  const int tid = threadIdx.x;
  unsigned k0 = split_key_elem(2u * step);
  unsigned k1 = split_key_elem(2u * step + 1u);
  const unsigned half = 256u * (unsigned)NV;  // (NB*NV)/2
  const float* scL = out + (size_t)NB * NS + (size_t)bl * NS * NV + (size_t)step * NV;
  const float* scH = out + (size_t)NB * NS + (size_t)bh * NS * NV + (size_t)step * NV;
  float bestL = -INFINITY, bestH = -INFINITY;
  int biL = 0, biH = 0;
  for (int v = tid; v < NV; v += 256) {
    unsigned j = (unsigned)bl * (unsigned)NV + (unsigned)v;
    unsigned y0, y1;
    threefry2x32(k0, k1, j, j + half, y0, y1);
    float vL = scL[v] + gumbel_from_bits(y0);
    float vH = scH[v] + gumbel_from_bits(y1);
    if (vL > bestL) { bestL = vL; biL = v; }  // strict > keeps first occurrence
    if (vH > bestH) { bestH = vH; biH = v; }
  }
  __shared__ float sv[256];
  __shared__ int si[256];
  __shared__ int widxL, widxH;
  // reduce L
  sv[tid] = bestL; si[tid] = biL;
  __syncthreads();
  for (int off = 128; off > 0; off >>= 1) {
    if (tid < off) {
      float v2 = sv[tid + off]; int i2 = si[tid + off];
      if (v2 > sv[tid] || (v2 == sv[tid] && i2 < si[tid])) { sv[tid] = v2; si[tid] = i2; }
    }
    __syncthreads();
  }
  if (tid == 0) { widxL = si[0]; out[bl * NS + step] = (float)si[0]; }
  __syncthreads();
  // reduce H
  sv[tid] = bestH; si[tid] = biH;
  __syncthreads();
  for (int off = 128; off > 0; off >>= 1) {
    if (tid < off) {
      float v2 = sv[tid + off]; int i2 = si[tid + off];
      if (v2 > sv[tid] || (v2 == sv[tid] && i2 < si[tid])) { sv[tid] = v2; si[tid] = i2; }
    }
    __syncthreads();
  }
  if (tid == 0) { widxH = si[0]; out[bh * NS + step] = (float)si[0]; }
  __syncthreads();
  if (tid < NOE) {
    order_emb[bl * NOE + tid] = order_embedding[(size_t)widxL * NOE + tid];
    order_emb[bh * NOE + tid] = order_embedding[(size_t)widxH * NOE + tid];
  }
}

extern "C" void kernel_launch(void* const* d_in, const int* in_sizes, int n_in,
                              void* d_out, int out_size, void* d_ws, size_t ws_size,
                              hipStream_t stream) {
  const float* enc          = (const float*)d_in[0];
  // d_in[1] = in_adj_phase (unused by reference)
  const int*   loc_idxs     = (const int*)d_in[2];
  const int*   order_masks  = (const int*)d_in[3];
  const float* power_1h     = (const float*)d_in[4];
  const float* order_embedding = (const float*)d_in[5];
  const float* power_W      = (const float*)d_in[6];
  const float* power_b      = (const float*)d_in[7];
  const float* W_ih         = (const float*)d_in[8];
  const float* W_hh         = (const float*)d_in[9];
  const float* b_ih         = (const float*)d_in[10];
  const float* b_hh         = (const float*)d_in[11];
  const float* out_W        = (const float*)d_in[12];
  const float* out_b        = (const float*)d_in[13];
  const float* MA           = (const float*)d_in[14];

  float* ws        = (float*)d_ws;
  float* power_emb = ws;                       // NB*NPE
  float* h         = power_emb + NB * NPE;     // NB*NH
  float* c         = h + NB * NH;              // NB*NH
  float* order_emb = c + NB * NH;              // NB*NOE
  float* x         = order_emb + NB * NOE;     // NB*NIN
  float* gates     = x + NB * NIN;             // NB*NG
  int*   invalid   = (int*)(gates + NB * NG);  // NB

  float* out = (float*)d_out;

  // zero the recurrent state (h, c, order_emb are contiguous)
  hipMemsetAsync(h, 0, sizeof(float) * (size_t)NB * (NH + NH + NOE), stream);
  init_kernel<<<(NB * NPE + 255) / 256, 256, 0, stream>>>(
      power_1h, power_W, power_b, loc_idxs, power_emb, invalid);

  dim3 gGates((NG + BN - 1) / BN, NB / BM);
  dim3 gScores((NV + BN - 1) / BN, NB / BM);
  for (int s = 0; s < NS; ++s) {
    build_x_kernel<<<NB, 256, 0, stream>>>(loc_idxs, MA, enc, order_emb, power_emb, x, s);
    gates_kernel<<<gGates, 256, 0, stream>>>(x, h, W_ih, W_hh, b_ih, b_hh, gates);
    lstm_cell_kernel<<<(NB * NH + 255) / 256, 256, 0, stream>>>(gates, h, c);
    scores_kernel<<<gScores, 256, 0, stream>>>(h, out_W, out_b, order_masks, invalid, out, s);
    sample_kernel<<<NB / 2, 256, 0, stream>>>(out, order_embedding, order_emb, s);
  }
}

// Round 2
// 1941.782 us; speedup vs baseline: 1.8986x; 1.8986x over previous
//
#include <hip/hip_runtime.h>
#include <math.h>

// Problem constants
#define NB 512
#define NS 17
#define NL 81
#define NV 13030
#define NENC 240
#define NOE 80
#define NPE 60
#define NH 200
#define NIN 380
#define NG 800        // 4*H
#define KP 224        // padded K for scores GEMM (>=200, mult of 32)
#define KG 608        // padded K for gates GEMM: 224(h)+240(enc)+80(oe)+60(pe)+4
#define NVP 13056     // NV padded to 64 (204*64)
#define NGP 832       // NG padded to 64 (13*64)
#define NBLK 204      // NVP/64 n-blocks in scores grid

// xh (activation) column layout, bf16, row stride KG:
//   [0:200) h   [200:224) zero   [224:464) loc_enc   [464:544) order_emb
//   [544:604) power_emb   [604:608) zero
#define XH_ENC 224
#define XH_OE  464
#define XH_PE  544

typedef short bf8_t __attribute__((ext_vector_type(8)));   // 8 bf16 (4 VGPRs)
typedef float f4_t __attribute__((ext_vector_type(4)));

__device__ __forceinline__ unsigned short f2bf(float f) {
  unsigned u = __float_as_uint(f);
  unsigned r = (u + 0x7fffu + ((u >> 16) & 1u)) >> 16;
  return (unsigned short)r;
}

// ---------------- threefry2x32 ----------------
__device__ __host__ __forceinline__ unsigned rotl32h(unsigned x, int d) {
  return (x << d) | (x >> (32 - d));
}
__device__ __host__ __forceinline__ void threefry2x32(
    unsigned k0, unsigned k1, unsigned x0, unsigned x1,
    unsigned& y0, unsigned& y1) {
  unsigned ks2 = k0 ^ k1 ^ 0x1BD11BDAu;
  x0 += k0; x1 += k1;
#define TFR(r) { x0 += x1; x1 = rotl32h(x1, r); x1 ^= x0; }
  TFR(13) TFR(15) TFR(26) TFR(6)
  x0 += k1;  x1 += ks2 + 1u;
  TFR(17) TFR(29) TFR(16) TFR(24)
  x0 += ks2; x1 += k0 + 2u;
  TFR(13) TFR(15) TFR(26) TFR(6)
  x0 += k0;  x1 += k1 + 3u;
  TFR(17) TFR(29) TFR(16) TFR(24)
  x0 += k1;  x1 += ks2 + 4u;
  TFR(13) TFR(15) TFR(26) TFR(6)
  x0 += ks2; x1 += k0 + 5u;
#undef TFR
  y0 = x0; y1 = x1;
}

__device__ __forceinline__ float gumbel_from_bits(unsigned bits) {
  float u = __uint_as_float((bits >> 9) | 0x3f800000u) - 1.0f;
  if (u == 0.0f) u = 1.17549435e-38f;
  return -__logf(-__logf(u));
}

// ---------------- one-time prep kernels ----------------
__global__ void __launch_bounds__(256) prep_wcat_kernel(
    const float* __restrict__ W_ih, const float* __restrict__ W_hh,
    unsigned short* __restrict__ Wcat) {
  int t = blockIdx.x * 256 + threadIdx.x;
  if (t >= NGP * KG) return;
  int n = t / KG, k = t % KG;
  float v = 0.f;
  if (n < NG) {
    if (k < NH) v = W_hh[n * NH + k];
    else if (k >= XH_ENC && k < XH_PE + NPE) v = W_ih[n * NIN + (k - XH_ENC)];
  }
  Wcat[t] = f2bf(v);
}

__global__ void __launch_bounds__(256) prep_outw_kernel(
    const float* __restrict__ out_W, unsigned short* __restrict__ outWb) {
  int t = blockIdx.x * 256 + threadIdx.x;
  if (t >= NVP * KP) return;
  int n = t / KP, k = t % KP;
  outWb[t] = f2bf((n < NV && k < NH) ? out_W[n * NH + k] : 0.f);
}

__global__ void __launch_bounds__(256) misc_kernel(
    const float* __restrict__ power_1h, const float* __restrict__ power_W,
    const float* __restrict__ power_b, const int* __restrict__ loc_idxs,
    const float* __restrict__ b_ih, const float* __restrict__ b_hh,
    unsigned short* __restrict__ xh, float* __restrict__ bcat,
    int* __restrict__ invalid) {
  int t = blockIdx.x * 256 + threadIdx.x;
  if (t < NB * NPE) {
    int b = t / NPE, p = t % NPE;
    float a = power_b[p];
#pragma unroll
    for (int k = 0; k < 7; ++k) a = fmaf(power_1h[b * 7 + k], power_W[p * 7 + k], a);
    xh[(size_t)b * KG + XH_PE + p] = f2bf(a);
  }
  if (t < NG) bcat[t] = b_ih[t] + b_hh[t];
  if (t < NB) {
    bool any = false;
    for (int l = 0; l < NL; ++l) any = any || (loc_idxs[t * NL + l] != -1);
    invalid[t] = any ? 0 : 1;
  }
}

// ---------------- per-step: alignment + loc_enc into xh (bf16) --------------
__global__ void __launch_bounds__(256) build_x_kernel(
    const int* __restrict__ loc_idxs, const float* __restrict__ MA,
    const float* __restrict__ enc, unsigned short* __restrict__ xh, int step) {
  __shared__ float sel[NL];
  __shared__ float aln[NL];
  __shared__ float denom;
  const int b = blockIdx.x, tid = threadIdx.x;
  if (tid < NL) {
    int li = loc_idxs[b * NL + tid];
    sel[tid] = (li == step || li == -2) ? 1.0f : 0.0f;
  }
  __syncthreads();
  if (tid < NL) {
    float a = 0.f;
    for (int l = 0; l < NL; ++l) a = fmaf(sel[l], MA[l * NL + tid], a);
    aln[tid] = a;
  }
  __syncthreads();
  if (tid == 0) {
    float d = 0.f;
    for (int l = 0; l < NL; ++l) d += aln[l];
    denom = d;
  }
  __syncthreads();
  if (tid < NL) aln[tid] = (denom != 0.f) ? aln[tid] / denom : 0.0f;
  __syncthreads();
  if (tid < NENC) {
    const float* eb = enc + (size_t)b * NL * NENC + tid;
    float a = 0.f;
    for (int l = 0; l < NL; ++l) a = fmaf(aln[l], eb[(size_t)l * NENC], a);
    xh[(size_t)b * KG + XH_ENC + tid] = f2bf(a);
  }
}

// ---------------- MFMA NT GEMM core: per-wave 16x64 tile --------------------
// A: bf16 [M][lda], B: bf16 [N][ldb]; both K-contiguous. Wave computes rows
// m0w..m0w+15, cols n0..n0+63. acc[jf] covers n = n0+jf*16+tx, m = quad*4+reg.
__device__ __forceinline__ void mfma_nt_16x64(
    const unsigned short* __restrict__ A, const unsigned short* __restrict__ B,
    int lda, int ldb, int m0w, int n0, int nk, f4_t acc[4]) {
  const int lane = threadIdx.x & 63;
  const int tx = lane & 15, quad = lane >> 4;
  const unsigned short* ap = A + (size_t)(m0w + tx) * lda + quad * 8;
  const unsigned short* bp0 = B + (size_t)(n0 + tx) * ldb + quad * 8;
  for (int kc = 0; kc < nk; ++kc) {
    bf8_t a = *(const bf8_t*)(ap + kc * 32);
#pragma unroll
    for (int jf = 0; jf < 4; ++jf) {
      bf8_t b = *(const bf8_t*)(bp0 + (size_t)jf * 16 * ldb + kc * 32);
      acc[jf] = __builtin_amdgcn_mfma_f32_16x16x32_bf16(a, b, acc[jf], 0, 0, 0);
    }
  }
}

// ---------------- per-step: gates GEMM (M=512,N=800,K=608) ------------------
__global__ void __launch_bounds__(256) gates_kernel(
    const unsigned short* __restrict__ xh, const unsigned short* __restrict__ Wcat,
    const float* __restrict__ bcat, float* __restrict__ gates) {
  const int w = threadIdx.x >> 6;
  const int lane = threadIdx.x & 63;
  const int tx = lane & 15, quad = lane >> 4;
  const int m0w = blockIdx.y * 64 + w * 16;
  const int n0 = blockIdx.x * 64;
  f4_t acc[4] = {};
  mfma_nt_16x64(xh, Wcat, KG, KG, m0w, n0, KG / 32, acc);
#pragma unroll
  for (int jf = 0; jf < 4; ++jf) {
    int n = n0 + jf * 16 + tx;
    if (n >= NG) continue;
    float bias = bcat[n];
#pragma unroll
    for (int reg = 0; reg < 4; ++reg) {
      int m = m0w + quad * 4 + reg;
      gates[(size_t)m * NG + n] = acc[jf][reg] + bias;
    }
  }
}

// ---------------- per-step: LSTM cell; h -> xh bf16 ----------------
__global__ void __launch_bounds__(256) lstm_cell_kernel(
    const float* __restrict__ gates, unsigned short* __restrict__ xh,
    float* __restrict__ c) {
  int t = blockIdx.x * 256 + threadIdx.x;
  if (t >= NB * NH) return;
  int b = t / NH, j = t % NH;
  const float* g = gates + (size_t)b * NG;
  float gi = g[j], gf = g[NH + j], gg = g[2 * NH + j], go = g[3 * NH + j];
  float si = 1.f / (1.f + expf(-gi));
  float sf = 1.f / (1.f + expf(-gf));
  float so = 1.f / (1.f + expf(-go));
  float cn = sf * c[t] + si * tanhf(gg);
  float hn = so * tanhf(cn);
  c[t] = cn;
  xh[(size_t)b * KG + j] = f2bf(hn);
}

// ------ per-step: scores GEMM + mask + write + gumbel + partial argmax ------
__global__ void __launch_bounds__(256) scores_kernel(
    const unsigned short* __restrict__ xh, const unsigned short* __restrict__ outWb,
    const float* __restrict__ out_b, const int* __restrict__ order_masks,
    const int* __restrict__ invalid, float* __restrict__ out,
    float* __restrict__ pval, int* __restrict__ pidx,
    int step, unsigned k0, unsigned k1) {
  const int w = threadIdx.x >> 6;
  const int lane = threadIdx.x & 63;
  const int tx = lane & 15, quad = lane >> 4;
  const int m0w = blockIdx.y * 64 + w * 16;
  const int n0 = blockIdx.x * 64;
  f4_t acc[4] = {};
  mfma_nt_16x64(xh, outWb, KG, KP, m0w, n0, KP / 32, acc);

  float bias[4];
  int nn[4];
#pragma unroll
  for (int jf = 0; jf < 4; ++jf) {
    nn[jf] = n0 + jf * 16 + tx;
    bias[jf] = (nn[jf] < NV) ? out_b[nn[jf]] : 0.f;
  }

  float bval[4];
  int bidx[4];
#pragma unroll
  for (int reg = 0; reg < 4; ++reg) {
    const int m = m0w + quad * 4 + reg;
    const int inv = invalid[m];
    const int* mrow = order_masks + (size_t)m * NS * NV + (size_t)step * NV;
    float* orow = out + (size_t)NB * NS + ((size_t)m * NS + step) * (size_t)NV;
    float vals[4];
#pragma unroll
    for (int jf = 0; jf < 4; ++jf) {
      int n = nn[jf];
      float v = -1.0e8f;
      if (n < NV) {
        int msk = inv ? 1 : mrow[n];
        v = fminf(acc[jf][reg] + bias[jf], msk ? 9.0e8f : -1.0e8f);
        orow[n] = v;
      }
      vals[jf] = v;
    }
    // gumbel (threefry pairs over jf: (0,1) and (2,3))
    unsigned base = (unsigned)m * (unsigned)NV;
    unsigned y0, y1, y2, y3;
    threefry2x32(k0, k1, base + (unsigned)nn[0], base + (unsigned)nn[1], y0, y1);
    threefry2x32(k0, k1, base + (unsigned)nn[2], base + (unsigned)nn[3], y2, y3);
    float g[4] = {gumbel_from_bits(y0), gumbel_from_bits(y1),
                  gumbel_from_bits(y2), gumbel_from_bits(y3)};
    float bv = -INFINITY; int bi = 0;
#pragma unroll
    for (int jf = 0; jf < 4; ++jf) {
      float cnd = (nn[jf] < NV) ? vals[jf] + g[jf] : -INFINITY;
      if (cnd > bv) { bv = cnd; bi = nn[jf]; }
    }
    bval[reg] = bv; bidx[reg] = bi;
  }
  // reduce across the 16 lanes of this quad (xor 1,2,4,8 stays in-group)
#pragma unroll
  for (int s = 8; s >= 1; s >>= 1) {
#pragma unroll
    for (int reg = 0; reg < 4; ++reg) {
      float ov = __shfl_xor(bval[reg], s);
      int oi = __shfl_xor(bidx[reg], s);
      if (ov > bval[reg]) { bval[reg] = ov; bidx[reg] = oi; }
    }
  }
#pragma unroll
  for (int reg = 0; reg < 4; ++reg) {
    if (tx == reg) {
      int m = m0w + quad * 4 + reg;
      pval[(size_t)m * NBLK + blockIdx.x] = bval[reg];
      pidx[(size_t)m * NBLK + blockIdx.x] = bidx[reg];
    }
  }
}

// ---------------- per-step: final argmax reduce + embedding gather ----------
__global__ void __launch_bounds__(256) sample_kernel(
    const float* __restrict__ pval, const int* __restrict__ pidx,
    const float* __restrict__ order_embedding, unsigned short* __restrict__ xh,
    float* __restrict__ out, int step) {
  const int m = blockIdx.x, tid = threadIdx.x;
  __shared__ float sv[256];
  __shared__ int si[256];
  float v = -INFINITY; int i = 0;
  if (tid < NBLK) { v = pval[(size_t)m * NBLK + tid]; i = pidx[(size_t)m * NBLK + tid]; }
  sv[tid] = v; si[tid] = i;
  __syncthreads();
  for (int off = 128; off > 0; off >>= 1) {
    if (tid < off) {
      float v2 = sv[tid + off]; int i2 = si[tid + off];
      if (v2 > sv[tid] || (v2 == sv[tid] && i2 < si[tid])) { sv[tid] = v2; si[tid] = i2; }
    }
    __syncthreads();
  }
  if (tid == 0) out[m * NS + step] = (float)si[0];
  if (tid < NOE) {
    int idx = si[0];
    xh[(size_t)m * KG + XH_OE + tid] = f2bf(order_embedding[(size_t)idx * NOE + tid]);
  }
}

extern "C" void kernel_launch(void* const* d_in, const int* in_sizes, int n_in,
                              void* d_out, int out_size, void* d_ws, size_t ws_size,
                              hipStream_t stream) {
  const float* enc          = (const float*)d_in[0];
  const int*   loc_idxs     = (const int*)d_in[2];
  const int*   order_masks  = (const int*)d_in[3];
  const float* power_1h     = (const float*)d_in[4];
  const float* order_embedding = (const float*)d_in[5];
  const float* power_W      = (const float*)d_in[6];
  const float* power_b      = (const float*)d_in[7];
  const float* W_ih         = (const float*)d_in[8];
  const float* W_hh         = (const float*)d_in[9];
  const float* b_ih         = (const float*)d_in[10];
  const float* b_hh         = (const float*)d_in[11];
  const float* out_W        = (const float*)d_in[12];
  const float* out_b        = (const float*)d_in[13];
  const float* MA           = (const float*)d_in[14];

  float* ws      = (float*)d_ws;
  float* c       = ws;                      // NB*NH
  float* gates   = c + NB * NH;             // NB*NG
  float* pval    = gates + NB * NG;         // NB*NBLK
  float* bcat    = pval + NB * NBLK;        // NG
  int*   pidx    = (int*)(bcat + NG);       // NB*NBLK
  int*   invalid = pidx + NB * NBLK;        // NB
  unsigned short* xh    = (unsigned short*)(invalid + NB);  // NB*KG bf16
  unsigned short* Wcat  = xh + (size_t)NB * KG;             // NGP*KG bf16
  unsigned short* outWb = Wcat + (size_t)NGP * KG;          // NVP*KP bf16

  float* out = (float*)d_out;

  // zero recurrent state: xh (h/oe/pads) + c
  hipMemsetAsync(xh, 0, sizeof(unsigned short) * (size_t)NB * KG, stream);
  hipMemsetAsync(c, 0, sizeof(float) * (size_t)NB * NH, stream);
  misc_kernel<<<(NB * NPE + 255) / 256, 256, 0, stream>>>(
      power_1h, power_W, power_b, loc_idxs, b_ih, b_hh, xh, bcat, invalid);
  prep_wcat_kernel<<<(NGP * KG + 255) / 256, 256, 0, stream>>>(W_ih, W_hh, Wcat);
  prep_outw_kernel<<<(NVP * KP + 255) / 256, 256, 0, stream>>>(out_W, outWb);

  // step keys (host-side threefry: deterministic, no device API)
  unsigned key[2 * NS];
  for (unsigned i = 0; i < NS; ++i) {
    unsigned y0, y1;
    threefry2x32(0u, 42u, i, i + NS, y0, y1);
    key[2 * i] = y0;
    threefry2x32(0u, 42u, i, i + NS, y0, y1);  // same block; lane1 of pair (i, i+NS)
    key[2 * i + 1] = y1;
  }

  dim3 gGates(NGP / 64, NB / 64);
  dim3 gScores(NBLK, NB / 64);
  for (int s = 0; s < NS; ++s) {
    build_x_kernel<<<NB, 256, 0, stream>>>(loc_idxs, MA, enc, xh, s);
    gates_kernel<<<gGates, 256, 0, stream>>>(xh, Wcat, bcat, gates);
    lstm_cell_kernel<<<(NB * NH + 255) / 256, 256, 0, stream>>>(gates, xh, c);
    scores_kernel<<<gScores, 256, 0, stream>>>(
        xh, outWb, out_b, order_masks, invalid, out, pval, pidx,
        s, key[2 * s], key[2 * s + 1]);
    sample_kernel<<<NB, 256, 0, stream>>>(pval, pidx, order_embedding, xh, out, s);
  }
}